// Round 7
// baseline (920.229 us; speedup 1.0000x reference)
//
#include <hip/hip_runtime.h>

#define NN 12288
#define FF 128
#define HH 64
#define CC 16
#define CAP 128

#define NBLD 2048                  // probe blocks (8/CU, no LDS -> 32 waves/CU)
#define NTHR (NBLD * 256)          // 524288 threads
#define NV4  (NN * (NN / 4))       // 37,748,736 vec4 in adj
#define NIT  (NV4 / NTHR)          // 72 per-thread vec4s = 9 chunks of 8

typedef float f32x4 __attribute__((ext_vector_type(4)));

// ---------------------------------------------------------------------------
// k_probe: PURE-READ bandwidth probe of adj — the decisive experiment.
// Six build variants (R0-R6: block-per-row / wave-per-row / global sweep /
// +-atomics / +-ballots / branch-free byte-mask) ALL read adj at ~1.6 TB/s
// while the harness fill writes 6.3 TB/s. This kernel is the most
// read-optimal shape possible: 8 INDEPENDENT 16B loads in flight per wave
// (8 KB/wave, 2.7x R6's depth), XOR-consumed (integer, 4 ops/load), no
// cross-lane ops, no data-dependent control flow, one 4B store per thread
// at the very end. dur_us - 767 (R2 baseline, reused verbatim below) reads
// out t_probe directly:  ~100us -> reads can be fast, rebuild the scan like
// this;  ~350us -> read wall confirmed for ANY shape -> we are at roofline.
// ---------------------------------------------------------------------------
__global__ __launch_bounds__(256) void k_probe(const uint4* __restrict__ av,
                                               unsigned* __restrict__ sink) {
    unsigned vi = blockIdx.x * 256 + threadIdx.x;   // vec4 idx, stride NTHR
    unsigned ax = 0, ay = 0, az = 0, aw = 0;
    #pragma unroll 1
    for (int ch = 0; ch < NIT / 8; ++ch) {          // 9 chunks
        const uint4 v0 = av[vi];
        const uint4 v1 = av[vi + 1u * NTHR];
        const uint4 v2 = av[vi + 2u * NTHR];
        const uint4 v3 = av[vi + 3u * NTHR];
        const uint4 v4 = av[vi + 4u * NTHR];
        const uint4 v5 = av[vi + 5u * NTHR];
        const uint4 v6 = av[vi + 6u * NTHR];
        const uint4 v7 = av[vi + 7u * NTHR];        // 8 loads in flight
        ax ^= v0.x ^ v1.x ^ v2.x ^ v3.x ^ v4.x ^ v5.x ^ v6.x ^ v7.x;
        ay ^= v0.y ^ v1.y ^ v2.y ^ v3.y ^ v4.y ^ v5.y ^ v6.y ^ v7.y;
        az ^= v0.z ^ v1.z ^ v2.z ^ v3.z ^ v4.z ^ v5.z ^ v6.z ^ v7.z;
        aw ^= v0.w ^ v1.w ^ v2.w ^ v3.w ^ v4.w ^ v5.w ^ v6.w ^ v7.w;
        vi += 8u * NTHR;
    }
    sink[blockIdx.x * 256 + threadIdx.x] = ax ^ ay ^ az ^ aw;  // keep loads live
}

// ===========================================================================
// R2 pipeline verbatim below (767 us best measured) — unchanged semantics.
// ===========================================================================
__global__ __launch_bounds__(256) void k_build(const float* __restrict__ adj,
                                               int* __restrict__ cnt,
                                               float* __restrict__ dinv,
                                               int* __restrict__ nbr) {
    const int i = blockIdx.x;
    __shared__ int s_cnt;
    if (threadIdx.x == 0) s_cnt = 0;
    __syncthreads();
    const f32x4* row = (const f32x4*)(adj + (size_t)i * NN);
    int* my_nbr = nbr + (size_t)i * CAP;
    const int lane = threadIdx.x & 63;
    const unsigned long long lt_mask = (lane == 63) ? ~0ull >> 1
                                                    : (1ull << lane) - 1ull;
    #pragma unroll
    for (int it = 0; it < (NN / 4 / 256); ++it) {
        const int vi = it * 256 + threadIdx.x;
        const f32x4 v = row[vi];
        #pragma unroll
        for (int q = 0; q < 4; ++q) {
            const unsigned long long m = __ballot(v[q] != 0.f);
            if (m) {
                int base = 0;
                if (lane == __ffsll((long long)m) - 1)
                    base = atomicAdd(&s_cnt, __popcll(m));
                base = __shfl(base, __ffsll((long long)m) - 1);
                if (v[q] != 0.f) {
                    const int s = base + __popcll(m & lt_mask);
                    if (s < CAP) my_nbr[s] = vi * 4 + q;
                }
            }
        }
    }
    __syncthreads();
    if (threadIdx.x == 0) {
        cnt[i] = min(s_cnt, CAP);
        dinv[i] = 1.0f / sqrtf((float)(s_cnt + 1));
    }
}

__global__ __launch_bounds__(512) void k_proj(const float* __restrict__ W1,
                                              const float* __restrict__ dinv,
                                              const float* __restrict__ x,
                                              float* __restrict__ xp) {
    __shared__ float s_W1[FF * HH];
    __shared__ float s_x[8][FF];
    {
        const f32x4* Wv = (const f32x4*)W1;
        f32x4* Sv = (f32x4*)s_W1;
        for (int t = threadIdx.x; t < FF * HH / 4; t += 512) Sv[t] = Wv[t];
    }
    const int wave = threadIdx.x >> 6;
    const int lane = threadIdx.x & 63;
    const int i = blockIdx.x * 8 + wave;
    const float2 xv = *(const float2*)(x + (size_t)i * FF + 2 * lane);
    s_x[wave][2 * lane]     = xv.x;
    s_x[wave][2 * lane + 1] = xv.y;
    __syncthreads();
    float h = 0.f;
    #pragma unroll 8
    for (int f = 0; f < FF; ++f) h += s_x[wave][f] * s_W1[f * HH + lane];
    xp[(size_t)i * HH + lane] = dinv[i] * h;
}

__global__ __launch_bounds__(512) void k_agg1(const int* __restrict__ cnt,
                                              const float* __restrict__ dinv,
                                              const int* __restrict__ nbr,
                                              const float* __restrict__ xp,
                                              float* __restrict__ h1s) {
    const int wave = threadIdx.x >> 6;
    const int lane = threadIdx.x & 63;
    const int i = blockIdx.x * 8 + wave;
    const float di = dinv[i];
    float a = xp[(size_t)i * HH + lane];
    const int c = cnt[i];
    const int* nb = nbr + (size_t)i * CAP;
    int k = 0;
    for (; k + 4 <= c; k += 4) {
        const int4 j4 = *(const int4*)(nb + k);
        const float a0 = xp[(size_t)j4.x * HH + lane];
        const float a1 = xp[(size_t)j4.y * HH + lane];
        const float a2 = xp[(size_t)j4.z * HH + lane];
        const float a3 = xp[(size_t)j4.w * HH + lane];
        a += (a0 + a1) + (a2 + a3);
    }
    for (; k < c; ++k) a += xp[(size_t)nb[k] * HH + lane];
    h1s[(size_t)i * HH + lane] = di * fmaxf(di * a, 0.f);
}

__global__ __launch_bounds__(512) void k_layer2(const float* __restrict__ W2,
                                                const int* __restrict__ cnt,
                                                const float* __restrict__ dinv,
                                                const int* __restrict__ nbr,
                                                const float* __restrict__ h1s,
                                                float* __restrict__ out) {
    __shared__ float s_W2[HH * CC];
    __shared__ float s_a[8][HH];
    for (int t = threadIdx.x; t < HH * CC; t += 512) s_W2[t] = W2[t];
    __syncthreads();
    const int wave = threadIdx.x >> 6;
    const int lane = threadIdx.x & 63;
    const int i = blockIdx.x * 8 + wave;
    float a = h1s[(size_t)i * HH + lane];
    const int c = cnt[i];
    const int* nb = nbr + (size_t)i * CAP;
    int k = 0;
    for (; k + 4 <= c; k += 4) {
        const int4 j4 = *(const int4*)(nb + k);
        const float a0 = h1s[(size_t)j4.x * HH + lane];
        const float a1 = h1s[(size_t)j4.y * HH + lane];
        const float a2 = h1s[(size_t)j4.z * HH + lane];
        const float a3 = h1s[(size_t)j4.w * HH + lane];
        a += (a0 + a1) + (a2 + a3);
    }
    for (; k < c; ++k) a += h1s[(size_t)nb[k] * HH + lane];
    s_a[wave][lane] = a * dinv[i];
    __syncthreads();
    float h = 0.f;
    if (lane < CC) {
        #pragma unroll
        for (int o = 0; o < HH; ++o) h += s_a[wave][o] * s_W2[o * CC + lane];
        h = fmaxf(h, 0.f);
    }
    float m = h;
    for (int d = 8; d >= 1; d >>= 1) m = fmaxf(m, __shfl_xor(m, d, 16));
    const float e = expf(h - m);
    float s = e;
    for (int d = 8; d >= 1; d >>= 1) s += __shfl_xor(s, d, 16);
    const float r = (h - m) - logf(s);
    if (lane < CC) out[(size_t)i * CC + lane] = r;
}

// ---------------------------------------------------------------------------
// Workspace: sink[NTHR] u32 (2 MB, probe checksum, dead) | cnt | dinv |
//            nbr[NN*CAP] | xp | h1s   — ~14.6 MB.
// ---------------------------------------------------------------------------
extern "C" void kernel_launch(void* const* d_in, const int* in_sizes, int n_in,
                              void* d_out, int out_size, void* d_ws, size_t ws_size,
                              hipStream_t stream) {
    const float* x   = (const float*)d_in[0];
    const float* adj = (const float*)d_in[1];
    const float* W1  = (const float*)d_in[2];
    const float* W2  = (const float*)d_in[3];
    float* out = (float*)d_out;

    char* p = (char*)d_ws;
    unsigned* sink = (unsigned*)p;  p += (size_t)NTHR * sizeof(unsigned);
    int*   cnt  = (int*)p;          p += (size_t)NN * sizeof(int);
    float* dinv = (float*)p;        p += (size_t)NN * sizeof(float);
    int*   nbr  = (int*)p;          p += (size_t)NN * CAP * sizeof(int);
    float* xp   = (float*)p;        p += (size_t)NN * HH * sizeof(float);
    float* h1s  = (float*)p;

    k_probe<<<NBLD, 256, 0, stream>>>((const uint4*)adj, sink);
    k_build<<<NN, 256, 0, stream>>>(adj, cnt, dinv, nbr);
    k_proj<<<NN / 8, 512, 0, stream>>>(W1, dinv, x, xp);
    k_agg1<<<NN / 8, 512, 0, stream>>>(cnt, dinv, nbr, xp, h1s);
    k_layer2<<<NN / 8, 512, 0, stream>>>(W2, cnt, dinv, nbr, h1s, out);
}

// Round 9
// 824.525 us; speedup vs baseline: 1.1161x; 1.1161x over previous
//
#include <hip/hip_runtime.h>

#define NN 12288
#define FF 128
#define HH 64
#define CC 16
#define CAP 128

#define NBLD 2048                  // scan blocks: 8/CU, no LDS, ~48 VGPR -> 32 waves/CU
#define NWAVES (NBLD * 4)          // 8192 waves
#define NV4  (NN * (NN / 4))       // 37,748,736 vec4 in adj
#define NSB  (NV4 / 512)           // 73,728 superblocks of 512 vec4 (8 KB)
#define SBPW (NSB / NWAVES)        // 9 superblocks per wave, exact

typedef float f32x4 __attribute__((ext_vector_type(4)));

// ---------------------------------------------------------------------------
// k_scan v4 — PROBE-SHAPED (R7 measured: this read pattern = 4.0 TB/s vs the
// ~1.6 TB/s of every consume-per-load variant R0-R6; flight depth is the
// lever). Per iteration a wave owns one contiguous 8 KB superblock; lane l
// issues 8 BACK-TO-BACK coalesced 16B loads (each load instr = 1 KB contig),
// only then consumes: 4-bit nibble per vec4, 8 nibbles packed -> one u32,
// one coalesced 256 B store per wave per superblock. No ballot/atomic/LDS/
// data-dependent branch. Writes 18.9 MB total.
// Encoding: msk[sb*64+l] bit (4k+q) <=> adj[(sb*512 + k*64 + l)*4 + q] != 0.
// ---------------------------------------------------------------------------
__global__ __launch_bounds__(256) void k_scan(const f32x4* __restrict__ av,
                                              unsigned* __restrict__ msk) {
    const int lane = threadIdx.x & 63;
    const int gw   = blockIdx.x * 4 + (threadIdx.x >> 6);   // 0..8191

    #pragma unroll 1
    for (int it = 0; it < SBPW; ++it) {
        const unsigned sb = (unsigned)gw + (unsigned)it * NWAVES; // 64MB window
        const f32x4* b = av + (size_t)sb * 512 + lane;
        // 8 independent loads in flight (probe shape)
        const f32x4 v0 = b[0 * 64];
        const f32x4 v1 = b[1 * 64];
        const f32x4 v2 = b[2 * 64];
        const f32x4 v3 = b[3 * 64];
        const f32x4 v4 = b[4 * 64];
        const f32x4 v5 = b[5 * 64];
        const f32x4 v6 = b[6 * 64];
        const f32x4 v7 = b[7 * 64];
        unsigned m = 0;
        #define NIB(v, s) m |= ((v[0] != 0.f ? 1u : 0u) | (v[1] != 0.f ? 2u : 0u) \
                             |  (v[2] != 0.f ? 4u : 0u) | (v[3] != 0.f ? 8u : 0u)) << (s);
        NIB(v0, 0) NIB(v1, 4) NIB(v2, 8) NIB(v3, 12)
        NIB(v4, 16) NIB(v5, 20) NIB(v6, 24) NIB(v7, 28)
        #undef NIB
        msk[(size_t)sb * 64 + lane] = m;            // 256 B/wave, coalesced
    }
}

// ---------------------------------------------------------------------------
// k_compact: expand the 18.9 MB L2/LLC-resident nibble-mask into capped CSR.
// Wave per row: row r owns superblocks 6r..6r+5 -> words (6r+b)*64 + l.
// 6 coalesced u32 loads/lane; popc + wave prefix scan -> deterministic slot
// bases (no atomics); each lane serially expands its ~0.35 expected bits.
// R8 BUG FIXED HERE: neighbor index must be the ROW-LOCAL column.
// Row r's superblock b, lane l, bit t=4k+q  ->  local vec4 = b*512 + k*64 + l
// (the 6r*512 = r*3072 row base subtracted), column = local_vec4*4 + q.
// R8 used the GLOBAL vec4 index -> col = row*12288+col -> OOB gathers -> abort.
// ---------------------------------------------------------------------------
__global__ __launch_bounds__(256) void k_compact(const unsigned* __restrict__ msk,
                                                 int* __restrict__ cnt,
                                                 int* __restrict__ nbr) {
    const int wave = threadIdx.x >> 6;
    const int lane = threadIdx.x & 63;
    const int row  = blockIdx.x * 4 + wave;

    unsigned w[6];
    int c = 0;
    #pragma unroll
    for (int b = 0; b < 6; ++b) {
        w[b] = msk[(size_t)(6 * row + b) * 64 + lane];   // 256B/instr
        c += __popc(w[b]);
    }

    int incl = c;                               // wave inclusive prefix scan
    #pragma unroll
    for (int d = 1; d < 64; d <<= 1) {
        const int n = __shfl_up(incl, d);
        if (lane >= d) incl += n;
    }
    const int total = __shfl(incl, 63);
    int base = incl - c;                        // exclusive base for this lane

    int* my = nbr + (size_t)row * CAP;
    #pragma unroll
    for (int b = 0; b < 6; ++b) {
        unsigned x = w[b];
        const int v0 = b * 512 + lane;          // ROW-LOCAL vec4 (0..3071)
        while (x) {
            const int t = __ffs(x) - 1;         // t = 4k+q
            if (base < CAP) my[base] = ((v0 + ((t >> 2) << 6)) << 2) + (t & 3);
            ++base;
            x &= x - 1;
        }
    }
    if (lane == 0) cnt[row] = total;            // true degree (uncapped)
}

// ---------------------------------------------------------------------------
// k_proj: xp[i,:] = dinv_i * (x_i @ W1)   [64]   ((Ax)W1 == A(xW1))
// ---------------------------------------------------------------------------
__global__ __launch_bounds__(512) void k_proj(const float* __restrict__ W1,
                                              const int* __restrict__ cnt,
                                              const float* __restrict__ x,
                                              float* __restrict__ xp) {
    __shared__ float s_W1[FF * HH];   // 32 KB
    __shared__ float s_x[8][FF];      // 4 KB
    {
        const f32x4* Wv = (const f32x4*)W1;
        f32x4* Sv = (f32x4*)s_W1;
        for (int t = threadIdx.x; t < FF * HH / 4; t += 512) Sv[t] = Wv[t];
    }
    const int wave = threadIdx.x >> 6;
    const int lane = threadIdx.x & 63;
    const int i = blockIdx.x * 8 + wave;

    const float2 xv = *(const float2*)(x + (size_t)i * FF + 2 * lane);
    s_x[wave][2 * lane]     = xv.x;
    s_x[wave][2 * lane + 1] = xv.y;
    __syncthreads();
    float h = 0.f;
    #pragma unroll 8
    for (int f = 0; f < FF; ++f) h += s_x[wave][f] * s_W1[f * HH + lane];
    const float di = 1.0f / sqrtf((float)(cnt[i] + 1));   // +1 = self loop
    xp[(size_t)i * HH + lane] = di * h;
}

// ---------------------------------------------------------------------------
// k_agg1: h1s[i,:] = dinv_i * relu(dinv_i * (xp_i + sum_nbr xp_j))
// (trailing dinv_i pre-folds layer-2's left D^-1/2). int4 neighbor fetch ->
// 4 independent 256B gathers per wait. No LDS.
// ---------------------------------------------------------------------------
__global__ __launch_bounds__(512) void k_agg1(const int* __restrict__ cnt,
                                              const int* __restrict__ nbr,
                                              const float* __restrict__ xp,
                                              float* __restrict__ h1s) {
    const int wave = threadIdx.x >> 6;
    const int lane = threadIdx.x & 63;
    const int i = blockIdx.x * 8 + wave;

    const int c = min(cnt[i], CAP);
    const float di = 1.0f / sqrtf((float)(cnt[i] + 1));
    float a = xp[(size_t)i * HH + lane];  // self (already dinv_i-scaled)
    const int* nb = nbr + (size_t)i * CAP;

    int k = 0;
    for (; k + 4 <= c; k += 4) {
        const int4 j4 = *(const int4*)(nb + k);   // 16B-aligned (CAP*4 stride)
        const float a0 = xp[(size_t)j4.x * HH + lane];
        const float a1 = xp[(size_t)j4.y * HH + lane];
        const float a2 = xp[(size_t)j4.z * HH + lane];
        const float a3 = xp[(size_t)j4.w * HH + lane];
        a += (a0 + a1) + (a2 + a3);
    }
    for (; k < c; ++k) a += xp[(size_t)nb[k] * HH + lane];

    h1s[(size_t)i * HH + lane] = di * fmaxf(di * a, 0.f);
}

// ---------------------------------------------------------------------------
// k_layer2: agg2 = dinv_i*(h1s_i + sum_nbr h1s_j); out = log_softmax(relu(agg2@W2))
// ---------------------------------------------------------------------------
__global__ __launch_bounds__(512) void k_layer2(const float* __restrict__ W2,
                                                const int* __restrict__ cnt,
                                                const int* __restrict__ nbr,
                                                const float* __restrict__ h1s,
                                                float* __restrict__ out) {
    __shared__ float s_W2[HH * CC];   // 4 KB
    __shared__ float s_a[8][HH];      // 2 KB
    for (int t = threadIdx.x; t < HH * CC; t += 512) s_W2[t] = W2[t];
    __syncthreads();

    const int wave = threadIdx.x >> 6;
    const int lane = threadIdx.x & 63;
    const int i = blockIdx.x * 8 + wave;

    const int c = min(cnt[i], CAP);
    float a = h1s[(size_t)i * HH + lane];  // self
    const int* nb = nbr + (size_t)i * CAP;

    int k = 0;
    for (; k + 4 <= c; k += 4) {
        const int4 j4 = *(const int4*)(nb + k);
        const float a0 = h1s[(size_t)j4.x * HH + lane];
        const float a1 = h1s[(size_t)j4.y * HH + lane];
        const float a2 = h1s[(size_t)j4.z * HH + lane];
        const float a3 = h1s[(size_t)j4.w * HH + lane];
        a += (a0 + a1) + (a2 + a3);
    }
    for (; k < c; ++k) a += h1s[(size_t)nb[k] * HH + lane];
    s_a[wave][lane] = a * (1.0f / sqrtf((float)(cnt[i] + 1)));
    __syncthreads();

    float h = 0.f;
    if (lane < CC) {
        #pragma unroll
        for (int o = 0; o < HH; ++o) h += s_a[wave][o] * s_W2[o * CC + lane];
        h = fmaxf(h, 0.f);
    }
    // log_softmax across 16-lane groups (lanes>=16 compute on h=0, never stored)
    float m = h;
    for (int d = 8; d >= 1; d >>= 1) m = fmaxf(m, __shfl_xor(m, d, 16));
    const float e = expf(h - m);
    float s = e;
    for (int d = 8; d >= 1; d >>= 1) s += __shfl_xor(s, d, 16);
    const float r = (h - m) - logf(s);
    if (lane < CC) out[(size_t)i * CC + lane] = r;
}

// ---------------------------------------------------------------------------
// Workspace: cnt[NN] int | nbr[NN*CAP] int | msk[NV4/8] u32 (18.9 MB) |
//            xp[NN*HH] f32 | h1s[NN*HH] f32   — ~31.5 MB total.
// No memset needed: k_compact writes cnt unconditionally (no atomics).
// ---------------------------------------------------------------------------
extern "C" void kernel_launch(void* const* d_in, const int* in_sizes, int n_in,
                              void* d_out, int out_size, void* d_ws, size_t ws_size,
                              hipStream_t stream) {
    const float* x   = (const float*)d_in[0];
    const float* adj = (const float*)d_in[1];
    const float* W1  = (const float*)d_in[2];
    const float* W2  = (const float*)d_in[3];
    float* out = (float*)d_out;

    char* p = (char*)d_ws;
    int*      cnt = (int*)p;       p += (size_t)NN * sizeof(int);
    int*      nbr = (int*)p;       p += (size_t)NN * CAP * sizeof(int);
    unsigned* msk = (unsigned*)p;  p += (size_t)(NV4 / 8) * sizeof(unsigned);
    float*    xp  = (float*)p;     p += (size_t)NN * HH * sizeof(float);
    float*    h1s = (float*)p;

    k_scan<<<NBLD, 256, 0, stream>>>((const f32x4*)adj, msk);
    k_compact<<<NN / 4, 256, 0, stream>>>(msk, cnt, nbr);
    k_proj<<<NN / 8, 512, 0, stream>>>(W1, cnt, x, xp);
    k_agg1<<<NN / 8, 512, 0, stream>>>(cnt, nbr, xp, h1s);
    k_layer2<<<NN / 8, 512, 0, stream>>>(W2, cnt, nbr, h1s, out);
}

// Round 10
// 823.498 us; speedup vs baseline: 1.1175x; 1.0012x over previous
//
#include <hip/hip_runtime.h>

#define NN 12288
#define FF 128
#define HH 64
#define CC 16
#define CAP 128

#define NBLD 2048                  // scan blocks: 8/CU, no LDS -> 32 waves/CU
#define NWAVES (NBLD * 4)          // 8192 waves
#define NV4  (NN * (NN / 4))       // 37,748,736 vec4 in adj
#define NSB  (NV4 / 512)           // 73,728 superblocks of 512 vec4 (8 KB)
#define SBPW (NSB / NWAVES)        // 9 superblocks per wave, exact

typedef float f32x4 __attribute__((ext_vector_type(4)));

// ---------------------------------------------------------------------------
// k_scan v5 — PROBE-ISOMORPHIC. R7's probe read adj at 4.0 TB/s; R9's scan
// (same load shape) still ran ~1.6 TB/s. The two remaining differences are
// eliminated here:
//  (H1) NO STORES IN THE STREAMING LOOP. Stores share vmcnt with loads on
//       CDNA; a per-iteration store dependent on all 8 loads makes every
//       iteration wait out a write round-trip (flight depth -> ~1). The 9
//       nibble words are accumulated in registers and stored only at the end.
//  (H2) NO VCC/compare in the consume: nz(t) = ((t<<1) | (0-(t<<1))) >> 31
//       (t<<1 drops the sign bit -> -0.0 counts as zero; adj is {0.0,1.0}).
//       Pure int VALU, hazard-free, like the probe's XORs.
// Encoding unchanged: msk[sb*64+l] bit (4k+q) <=> adj[(sb*512+k*64+l)*4+q]!=0
// ---------------------------------------------------------------------------
__global__ __launch_bounds__(256) void k_scan(const uint4* __restrict__ av,
                                              unsigned* __restrict__ msk) {
    const int lane = threadIdx.x & 63;
    const int gw   = blockIdx.x * 4 + (threadIdx.x >> 6);   // 0..8191

    unsigned acc[SBPW];
    #pragma unroll 1
    for (int it = 0; it < SBPW; ++it) {
        const unsigned sb = (unsigned)gw + (unsigned)it * NWAVES;
        const uint4* b = av + (size_t)sb * 512 + lane;
        const uint4 v0 = b[0 * 64];
        const uint4 v1 = b[1 * 64];
        const uint4 v2 = b[2 * 64];
        const uint4 v3 = b[3 * 64];
        const uint4 v4 = b[4 * 64];
        const uint4 v5 = b[5 * 64];
        const uint4 v6 = b[6 * 64];
        const uint4 v7 = b[7 * 64];          // 8 independent loads in flight
        unsigned m = 0;
        #define NZ(t)      ((((t) << 1) | (0u - ((t) << 1))) >> 31)
        #define NIB(v, s)  m |= (NZ((v).x) | (NZ((v).y) << 1) \
                              | (NZ((v).z) << 2) | (NZ((v).w) << 3)) << (s);
        NIB(v0, 0)  NIB(v1, 4)  NIB(v2, 8)  NIB(v3, 12)
        NIB(v4, 16) NIB(v5, 20) NIB(v6, 24) NIB(v7, 28)
        #undef NIB
        #undef NZ
        acc[it] = m;                         // register only — no store here
    }
    // all stores at kernel end (9 coalesced 256 B wave-stores)
    #pragma unroll
    for (int it = 0; it < SBPW; ++it)
        msk[(size_t)((unsigned)gw + (unsigned)it * NWAVES) * 64 + lane] = acc[it];
}

// ---------------------------------------------------------------------------
// k_compact (proven in R9): expand the 18.9 MB L2/LLC-resident nibble-mask
// into capped CSR. Wave per row; 6 coalesced u32 loads/lane; popc + wave
// prefix scan -> deterministic slot bases (no atomics); lane expands its
// ~0.35 expected bits. Row-LOCAL column: superblock b, lane l, bit t=4k+q
// -> local vec4 = b*512 + k*64 + l, column = vec4*4 + q.
// ---------------------------------------------------------------------------
__global__ __launch_bounds__(256) void k_compact(const unsigned* __restrict__ msk,
                                                 int* __restrict__ cnt,
                                                 int* __restrict__ nbr) {
    const int wave = threadIdx.x >> 6;
    const int lane = threadIdx.x & 63;
    const int row  = blockIdx.x * 4 + wave;

    unsigned w[6];
    int c = 0;
    #pragma unroll
    for (int b = 0; b < 6; ++b) {
        w[b] = msk[(size_t)(6 * row + b) * 64 + lane];   // 256B/instr
        c += __popc(w[b]);
    }

    int incl = c;                               // wave inclusive prefix scan
    #pragma unroll
    for (int d = 1; d < 64; d <<= 1) {
        const int n = __shfl_up(incl, d);
        if (lane >= d) incl += n;
    }
    const int total = __shfl(incl, 63);
    int base = incl - c;                        // exclusive base for this lane

    int* my = nbr + (size_t)row * CAP;
    #pragma unroll
    for (int b = 0; b < 6; ++b) {
        unsigned x = w[b];
        const int v0 = b * 512 + lane;          // ROW-LOCAL vec4 (0..3071)
        while (x) {
            const int t = __ffs(x) - 1;         // t = 4k+q
            if (base < CAP) my[base] = ((v0 + ((t >> 2) << 6)) << 2) + (t & 3);
            ++base;
            x &= x - 1;
        }
    }
    if (lane == 0) cnt[row] = total;            // true degree (uncapped)
}

// ---------------------------------------------------------------------------
// k_proj: xp[i,:] = dinv_i * (x_i @ W1)   [64]   ((Ax)W1 == A(xW1))
// ---------------------------------------------------------------------------
__global__ __launch_bounds__(512) void k_proj(const float* __restrict__ W1,
                                              const int* __restrict__ cnt,
                                              const float* __restrict__ x,
                                              float* __restrict__ xp) {
    __shared__ float s_W1[FF * HH];   // 32 KB
    __shared__ float s_x[8][FF];      // 4 KB
    {
        const f32x4* Wv = (const f32x4*)W1;
        f32x4* Sv = (f32x4*)s_W1;
        for (int t = threadIdx.x; t < FF * HH / 4; t += 512) Sv[t] = Wv[t];
    }
    const int wave = threadIdx.x >> 6;
    const int lane = threadIdx.x & 63;
    const int i = blockIdx.x * 8 + wave;

    const float2 xv = *(const float2*)(x + (size_t)i * FF + 2 * lane);
    s_x[wave][2 * lane]     = xv.x;
    s_x[wave][2 * lane + 1] = xv.y;
    __syncthreads();
    float h = 0.f;
    #pragma unroll 8
    for (int f = 0; f < FF; ++f) h += s_x[wave][f] * s_W1[f * HH + lane];
    const float di = 1.0f / sqrtf((float)(cnt[i] + 1));   // +1 = self loop
    xp[(size_t)i * HH + lane] = di * h;
}

// ---------------------------------------------------------------------------
// k_agg1: h1s[i,:] = dinv_i * relu(dinv_i * (xp_i + sum_nbr xp_j))
// (trailing dinv_i pre-folds layer-2's left D^-1/2). int4 neighbor fetch ->
// 4 independent 256B gathers per wait. No LDS.
// ---------------------------------------------------------------------------
__global__ __launch_bounds__(512) void k_agg1(const int* __restrict__ cnt,
                                              const int* __restrict__ nbr,
                                              const float* __restrict__ xp,
                                              float* __restrict__ h1s) {
    const int wave = threadIdx.x >> 6;
    const int lane = threadIdx.x & 63;
    const int i = blockIdx.x * 8 + wave;

    const int c = min(cnt[i], CAP);
    const float di = 1.0f / sqrtf((float)(cnt[i] + 1));
    float a = xp[(size_t)i * HH + lane];  // self (already dinv_i-scaled)
    const int* nb = nbr + (size_t)i * CAP;

    int k = 0;
    for (; k + 4 <= c; k += 4) {
        const int4 j4 = *(const int4*)(nb + k);   // 16B-aligned (CAP*4 stride)
        const float a0 = xp[(size_t)j4.x * HH + lane];
        const float a1 = xp[(size_t)j4.y * HH + lane];
        const float a2 = xp[(size_t)j4.z * HH + lane];
        const float a3 = xp[(size_t)j4.w * HH + lane];
        a += (a0 + a1) + (a2 + a3);
    }
    for (; k < c; ++k) a += xp[(size_t)nb[k] * HH + lane];

    h1s[(size_t)i * HH + lane] = di * fmaxf(di * a, 0.f);
}

// ---------------------------------------------------------------------------
// k_layer2: agg2 = dinv_i*(h1s_i + sum_nbr h1s_j); out = log_softmax(relu(agg2@W2))
// ---------------------------------------------------------------------------
__global__ __launch_bounds__(512) void k_layer2(const float* __restrict__ W2,
                                                const int* __restrict__ cnt,
                                                const int* __restrict__ nbr,
                                                const float* __restrict__ h1s,
                                                float* __restrict__ out) {
    __shared__ float s_W2[HH * CC];   // 4 KB
    __shared__ float s_a[8][HH];      // 2 KB
    for (int t = threadIdx.x; t < HH * CC; t += 512) s_W2[t] = W2[t];
    __syncthreads();

    const int wave = threadIdx.x >> 6;
    const int lane = threadIdx.x & 63;
    const int i = blockIdx.x * 8 + wave;

    const int c = min(cnt[i], CAP);
    float a = h1s[(size_t)i * HH + lane];  // self
    const int* nb = nbr + (size_t)i * CAP;

    int k = 0;
    for (; k + 4 <= c; k += 4) {
        const int4 j4 = *(const int4*)(nb + k);
        const float a0 = h1s[(size_t)j4.x * HH + lane];
        const float a1 = h1s[(size_t)j4.y * HH + lane];
        const float a2 = h1s[(size_t)j4.z * HH + lane];
        const float a3 = h1s[(size_t)j4.w * HH + lane];
        a += (a0 + a1) + (a2 + a3);
    }
    for (; k < c; ++k) a += h1s[(size_t)nb[k] * HH + lane];
    s_a[wave][lane] = a * (1.0f / sqrtf((float)(cnt[i] + 1)));
    __syncthreads();

    float h = 0.f;
    if (lane < CC) {
        #pragma unroll
        for (int o = 0; o < HH; ++o) h += s_a[wave][o] * s_W2[o * CC + lane];
        h = fmaxf(h, 0.f);
    }
    // log_softmax across 16-lane groups (lanes>=16 compute on h=0, never stored)
    float m = h;
    for (int d = 8; d >= 1; d >>= 1) m = fmaxf(m, __shfl_xor(m, d, 16));
    const float e = expf(h - m);
    float s = e;
    for (int d = 8; d >= 1; d >>= 1) s += __shfl_xor(s, d, 16);
    const float r = (h - m) - logf(s);
    if (lane < CC) out[(size_t)i * CC + lane] = r;
}

// ---------------------------------------------------------------------------
// Workspace: cnt[NN] int | nbr[NN*CAP] int | msk[NV4/8] u32 (18.9 MB) |
//            xp[NN*HH] f32 | h1s[NN*HH] f32   — ~31.5 MB total.
// No memset needed: k_compact writes cnt unconditionally (no atomics).
// ---------------------------------------------------------------------------
extern "C" void kernel_launch(void* const* d_in, const int* in_sizes, int n_in,
                              void* d_out, int out_size, void* d_ws, size_t ws_size,
                              hipStream_t stream) {
    const float* x   = (const float*)d_in[0];
    const float* adj = (const float*)d_in[1];
    const float* W1  = (const float*)d_in[2];
    const float* W2  = (const float*)d_in[3];
    float* out = (float*)d_out;

    char* p = (char*)d_ws;
    int*      cnt = (int*)p;       p += (size_t)NN * sizeof(int);
    int*      nbr = (int*)p;       p += (size_t)NN * CAP * sizeof(int);
    unsigned* msk = (unsigned*)p;  p += (size_t)(NV4 / 8) * sizeof(unsigned);
    float*    xp  = (float*)p;     p += (size_t)NN * HH * sizeof(float);
    float*    h1s = (float*)p;

    k_scan<<<NBLD, 256, 0, stream>>>((const uint4*)adj, msk);
    k_compact<<<NN / 4, 256, 0, stream>>>(msk, cnt, nbr);
    k_proj<<<NN / 8, 512, 0, stream>>>(W1, cnt, x, xp);
    k_agg1<<<NN / 8, 512, 0, stream>>>(cnt, nbr, xp, h1s);
    k_layer2<<<NN / 8, 512, 0, stream>>>(W2, cnt, nbr, h1s, out);
}